// Round 3
// baseline (322.112 us; speedup 1.0000x reference)
//
#include <hip/hip_runtime.h>
#include <hip/hip_bf16.h>
#include <stdint.h>

#define K_DIM 4096
#define N_DIM 8192

typedef __attribute__((ext_vector_type(8))) __bf16 bf16x8;
typedef __attribute__((ext_vector_type(4))) float f32x4;

// ---------- quantization: nearest of {0,±1,±.5,±.333333,±.2,±.142857,±.090909,±.076923} ----------
// Tie-break matches the reference's first-min scan over the LUT:
//   boundary to 0 (index 0 seen first)          -> strict >
//   boundaries between nonzero magnitudes (larger magnitude = lower index) -> >=
__device__ __forceinline__ float quantize1(float w, float scale) {
    float ws = w / scale;
    float a  = fabsf(ws);
    float v  = 0.0f;
    v = (a >  0.0384615f) ? 0.076923f : v;
    v = (a >= 0.0839160f) ? 0.090909f : v;
    v = (a >= 0.1168830f) ? 0.142857f : v;
    v = (a >= 0.1714285f) ? 0.2f      : v;
    v = (a >= 0.2666665f) ? 0.333333f : v;
    v = (a >= 0.4166665f) ? 0.5f      : v;
    v = (a >= 0.75f)      ? 1.0f      : v;
    v = copysignf(v, ws);
    return v * scale;
}

__device__ __forceinline__ unsigned short to_bf16(float f) {
    unsigned int u = __float_as_uint(f);
    u += 0x7FFFu + ((u >> 16) & 1u);   // RNE
    return (unsigned short)(u >> 16);
}

// ---------- pass 1a: quantize W (fp32) -> bf16 in d_ws ----------
__global__ void quant_w_kernel(const float* __restrict__ W,
                               const float* __restrict__ scale_p,
                               unsigned short* __restrict__ Wq, int n4) {
    const float s = scale_p[0];
    int idx    = blockIdx.x * blockDim.x + threadIdx.x;
    int stride = gridDim.x * blockDim.x;
    const float4* W4 = (const float4*)W;
    ushort4* Q4 = (ushort4*)Wq;
    for (int i = idx; i < n4; i += stride) {
        float4 w = W4[i];
        ushort4 q;
        q.x = to_bf16(quantize1(w.x, s));
        q.y = to_bf16(quantize1(w.y, s));
        q.z = to_bf16(quantize1(w.z, s));
        q.w = to_bf16(quantize1(w.w, s));
        Q4[i] = q;
    }
}

// ---------- pass 1b: convert x (fp32) -> bf16 in d_ws ----------
__global__ void conv_x_kernel(const float* __restrict__ X,
                              unsigned short* __restrict__ Xb, int n4) {
    int idx    = blockIdx.x * blockDim.x + threadIdx.x;
    int stride = gridDim.x * blockDim.x;
    const float4* X4 = (const float4*)X;
    ushort4* Q4 = (ushort4*)Xb;
    for (int i = idx; i < n4; i += stride) {
        float4 w = X4[i];
        ushort4 q;
        q.x = to_bf16(w.x); q.y = to_bf16(w.y);
        q.z = to_bf16(w.z); q.w = to_bf16(w.w);
        Q4[i] = q;
    }
}

// ---------- pass 2: bf16 GEMM, C[M,N] = A[M,K] * B[N,K]^T ----------
// 128x128 tile, BK=32, 4 waves (2x2), wave tile 64x64 = 4x4 frags of 16x16x32.
// LDS row stride padded to 80 B (64 B data + one 16 B pad slot per row):
//   frag-read bank group = (l16*20 + quad*4) % 32 -> period-8 full-bank tiling,
//   worst aliasing 2-way (free, m136). Fixes the 64 B-stride 8-way conflicts
//   that made R1/R2 LDS-pipe-bound (12.6M conflict cycles, both at 103 us).
// Staging keeps global_load_lds (dest = wave base + lane*16): slot s holds
//   row = s/5, chunk = min(s%5,3); pad slots duplicate chunk 0 (harmless).
__global__ __launch_bounds__(256) void gemm_bt_bf16(
        const unsigned short* __restrict__ A,   // [M][K] bf16 bits
        const unsigned short* __restrict__ B,   // [N][K] bf16 bits
        float* __restrict__ C, int M) {
    __shared__ uint4 sA[640];                   // 128 rows x 80 B = 10 KB
    __shared__ uint4 sB[640];

    const int tid  = threadIdx.x;
    const int w    = tid >> 6;
    const int lane = tid & 63;
    const int quad = lane >> 4;
    const int l16  = lane & 15;
    const int wm   = w >> 1;                    // 2x2 wave grid
    const int wn   = w & 1;

    const int ntile = blockIdx.x & 63;          // N/128 = 64
    const int mtile = blockIdx.x >> 6;          // M/128
    const int m0 = mtile * 128;
    const int n0 = ntile * 128;

    f32x4 acc[4][4];
    const f32x4 z = {0.f, 0.f, 0.f, 0.f};
#pragma unroll
    for (int i = 0; i < 4; ++i)
#pragma unroll
        for (int j = 0; j < 4; ++j) acc[i][j] = z;

    const char* Abase = (const char*)A;
    const char* Bbase = (const char*)B;
    char* sAb = (char*)sA;
    char* sBb = (char*)sB;

    for (int k0 = 0; k0 < K_DIM; k0 += 32) {
        // stage A + B: 640 slots each, 16 B per lane. Pass p covers slots
        // p*256+tid; pass 2 is waves 0-1 only (wave-uniform branch).
#pragma unroll
        for (int p = 0; p < 3; ++p) {
            if (p < 2 || w < 2) {
                int c   = p * 256 + tid;        // slot index < 640
                int row = c / 5;
                int sub = c - row * 5;
                int kc  = (sub < 4) ? sub : 0;
                const char* ga = Abase + ((size_t)(m0 + row) * K_DIM + k0) * 2 + kc * 16;
                const char* gb = Bbase + ((size_t)(n0 + row) * K_DIM + k0) * 2 + kc * 16;
                char* la = sAb + (p * 256 + w * 64) * 16;
                char* lb = sBb + (p * 256 + w * 64) * 16;
                __builtin_amdgcn_global_load_lds((const __attribute__((address_space(1))) void*)ga,
                                                 (__attribute__((address_space(3))) void*)la, 16, 0, 0);
                __builtin_amdgcn_global_load_lds((const __attribute__((address_space(1))) void*)gb,
                                                 (__attribute__((address_space(3))) void*)lb, 16, 0, 0);
            }
        }
        __syncthreads();

        bf16x8 af[4], bf[4];
#pragma unroll
        for (int i = 0; i < 4; ++i)
            af[i] = *(const bf16x8*)(sAb + (wm * 64 + i * 16 + l16) * 80 + quad * 16);
#pragma unroll
        for (int j = 0; j < 4; ++j)
            bf[j] = *(const bf16x8*)(sBb + (wn * 64 + j * 16 + l16) * 80 + quad * 16);
#pragma unroll
        for (int mi = 0; mi < 4; ++mi)
#pragma unroll
            for (int ni = 0; ni < 4; ++ni)
                acc[mi][ni] = __builtin_amdgcn_mfma_f32_16x16x32_bf16(af[mi], bf[ni], acc[mi][ni], 0, 0, 0);
        __syncthreads();
    }

    // epilogue: D row = m (quad*4+reg), col = n (lane&15)  [verified mapping, m89/m91]
#pragma unroll
    for (int mi = 0; mi < 4; ++mi) {
#pragma unroll
        for (int ni = 0; ni < 4; ++ni) {
            int row = m0 + wm * 64 + mi * 16 + quad * 4;
            int col = n0 + wn * 64 + ni * 16 + l16;
#pragma unroll
            for (int r = 0; r < 4; ++r)
                C[(size_t)(row + r) * N_DIM + col] = acc[mi][ni][r];
        }
    }
}

// ---------- fallback (ws too small): quantize W in place (fp32), fp32 tiled GEMM ----------
__global__ void quant_w_inplace(float* W, const float* __restrict__ scale_p, int n4) {
    const float s = scale_p[0];
    int idx    = blockIdx.x * blockDim.x + threadIdx.x;
    int stride = gridDim.x * blockDim.x;
    float4* W4 = (float4*)W;
    for (int i = idx; i < n4; i += stride) {
        float4 w = W4[i];
        w.x = quantize1(w.x, s); w.y = quantize1(w.y, s);
        w.z = quantize1(w.z, s); w.w = quantize1(w.w, s);
        W4[i] = w;
    }
}

__global__ __launch_bounds__(256) void gemm_fp32_fb(const float* __restrict__ A,
                                                    const float* __restrict__ B,
                                                    float* __restrict__ C, int M) {
    __shared__ float sA[64][17];
    __shared__ float sB[64][17];
    int tid = threadIdx.x;
    int tx = tid & 15, ty = tid >> 4;
    int n0 = (blockIdx.x & 127) * 64;          // N/64 = 128
    int m0 = (blockIdx.x >> 7) * 64;
    float acc[4][4] = {};
    for (int k0 = 0; k0 < K_DIM; k0 += 16) {
#pragma unroll
        for (int i = 0; i < 4; ++i) {
            int e = tid + i * 256;
            int r = e >> 4, c = e & 15;
            sA[r][c] = A[(size_t)(m0 + r) * K_DIM + k0 + c];
            sB[r][c] = B[(size_t)(n0 + r) * K_DIM + k0 + c];
        }
        __syncthreads();
#pragma unroll
        for (int kk = 0; kk < 16; ++kk) {
            float a[4], b[4];
#pragma unroll
            for (int i = 0; i < 4; ++i) { a[i] = sA[ty * 4 + i][kk]; b[i] = sB[tx * 4 + i][kk]; }
#pragma unroll
            for (int i = 0; i < 4; ++i)
#pragma unroll
                for (int j = 0; j < 4; ++j) acc[i][j] += a[i] * b[j];
        }
        __syncthreads();
    }
#pragma unroll
    for (int i = 0; i < 4; ++i)
#pragma unroll
        for (int j = 0; j < 4; ++j)
            C[(size_t)(m0 + ty * 4 + i) * N_DIM + n0 + tx * 4 + j] = acc[i][j];
}

extern "C" void kernel_launch(void* const* d_in, const int* in_sizes, int n_in,
                              void* d_out, int out_size, void* d_ws, size_t ws_size,
                              hipStream_t stream) {
    const float* x     = (const float*)d_in[0];
    const float* W     = (const float*)d_in[1];
    const float* scale = (const float*)d_in[2];
    float* out = (float*)d_out;

    const int M = in_sizes[0] / K_DIM;                       // 1024
    const size_t wq_bytes = (size_t)N_DIM * K_DIM * 2;       // 64 MiB
    const size_t xb_bytes = (size_t)M * K_DIM * 2;           // 8 MiB

    if (ws_size >= wq_bytes + xb_bytes && (M % 128) == 0) {
        unsigned short* Wq = (unsigned short*)d_ws;
        unsigned short* Xb = (unsigned short*)((char*)d_ws + wq_bytes);
        int nW4 = (N_DIM * K_DIM) / 4;
        int nX4 = (M * K_DIM) / 4;
        hipLaunchKernelGGL(quant_w_kernel, dim3(2048), dim3(256), 0, stream, W, scale, Wq, nW4);
        hipLaunchKernelGGL(conv_x_kernel, dim3(1024), dim3(256), 0, stream, x, Xb, nX4);
        hipLaunchKernelGGL(gemm_bt_bf16, dim3((M / 128) * (N_DIM / 128)), dim3(256), 0, stream,
                           Xb, Wq, out, M);
    } else {
        int nW4 = (N_DIM * K_DIM) / 4;
        hipLaunchKernelGGL(quant_w_inplace, dim3(2048), dim3(256), 0, stream,
                           (float*)W, scale, nW4);
        hipLaunchKernelGGL(gemm_fp32_fb, dim3((M / 64) * (N_DIM / 64)), dim3(256), 0, stream,
                           x, W, out, M);
    }
}

// Round 4
// 222.048 us; speedup vs baseline: 1.4506x; 1.4506x over previous
//
#include <hip/hip_runtime.h>
#include <hip/hip_bf16.h>
#include <stdint.h>

#define K_DIM 4096
#define N_DIM 8192
#define NTILES (N_DIM / 128)          // 64 B-row tiles
#define KCHUNKS (K_DIM / 32)          // 128 K chunks (BK=32)
// flags: bit (ntile, kchunk) set iff that 128x32 tile of quantized B has any nonzero.
// Layout: flags[ntile*4 + kchunk/32] bit (kchunk%32). 64*4 uints = 1 KB.

typedef __attribute__((ext_vector_type(8))) __bf16 bf16x8;
typedef __attribute__((ext_vector_type(4))) float f32x4;

// ---------- quantization: nearest of {0,±1,±.5,±.333333,±.2,±.142857,±.090909,±.076923} ----------
// Tie-break matches the reference's first-min LUT scan:
//   boundary to 0 (index 0 first) -> strict >; between nonzero magnitudes -> >=
__device__ __forceinline__ float quantize1(float w, float scale) {
    float ws = w / scale;
    float a  = fabsf(ws);
    float v  = 0.0f;
    v = (a >  0.0384615f) ? 0.076923f : v;
    v = (a >= 0.0839160f) ? 0.090909f : v;
    v = (a >= 0.1168830f) ? 0.142857f : v;
    v = (a >= 0.1714285f) ? 0.2f      : v;
    v = (a >= 0.2666665f) ? 0.333333f : v;
    v = (a >= 0.4166665f) ? 0.5f      : v;
    v = (a >= 0.75f)      ? 1.0f      : v;
    v = copysignf(v, ws);
    return v * scale;
}

__device__ __forceinline__ unsigned short to_bf16(float f) {
    unsigned int u = __float_as_uint(f);
    u += 0x7FFFu + ((u >> 16) & 1u);   // RNE
    return (unsigned short)(u >> 16);
}

// ---------- pass 1a: quantize W (fp32) -> bf16 Wq + sparsity flags ----------
// Grid-stride by float4. A wave (64 lanes x 4 cols = 256 cols) always sits inside
// one row and one flag WORD (chunks c0..c0+7, c0%8==0, never straddles a 32-chunk
// word) -> wave-OR reduce, single atomicOr from lane 0. Wq written only for quads
// with a nonzero (skipped regions are never read by the gemm: flag bit is 0).
__global__ void quant_w_kernel(const float* __restrict__ W,
                               const float* __restrict__ scale_p,
                               unsigned short* __restrict__ Wq,
                               unsigned int* __restrict__ flags, int n4) {
    const float s = scale_p[0];
    int idx    = blockIdx.x * blockDim.x + threadIdx.x;
    int stride = gridDim.x * blockDim.x;
    const float4* W4 = (const float4*)W;
    ushort4* Q4 = (ushort4*)Wq;
    for (int i = idx; i < n4; i += stride) {
        float4 w = W4[i];
        float qx = quantize1(w.x, s);
        float qy = quantize1(w.y, s);
        float qz = quantize1(w.z, s);
        float qw = quantize1(w.w, s);
        bool nz = (qx != 0.f) | (qy != 0.f) | (qz != 0.f) | (qw != 0.f);
        if (nz) {
            ushort4 q;
            q.x = to_bf16(qx); q.y = to_bf16(qy);
            q.z = to_bf16(qz); q.w = to_bf16(qw);
            Q4[i] = q;
        }
        int col    = (i << 2) & (K_DIM - 1);
        int row    = (i << 2) >> 12;          // /K_DIM
        int kchunk = col >> 5;
        int ntile  = row >> 7;
        unsigned int mask = nz ? (1u << (kchunk & 31)) : 0u;
#pragma unroll
        for (int off = 32; off; off >>= 1) mask |= __shfl_down(mask, off, 64);
        if (((threadIdx.x & 63) == 0) && mask)
            atomicOr(&flags[ntile * 4 + (kchunk >> 5)], mask);
    }
}

// ---------- pass 1b: convert x (fp32) -> bf16 in d_ws ----------
__global__ void conv_x_kernel(const float* __restrict__ X,
                              unsigned short* __restrict__ Xb, int n4) {
    int idx    = blockIdx.x * blockDim.x + threadIdx.x;
    int stride = gridDim.x * blockDim.x;
    const float4* X4 = (const float4*)X;
    ushort4* Q4 = (ushort4*)Xb;
    for (int i = idx; i < n4; i += stride) {
        float4 w = X4[i];
        ushort4 q;
        q.x = to_bf16(w.x); q.y = to_bf16(w.y);
        q.z = to_bf16(w.z); q.w = to_bf16(w.w);
        Q4[i] = q;
    }
}

// ---------- pass 2: sparse-aware bf16 GEMM, C = A * Bq^T ----------
// R1 structure (128x128 tile, BK=32, 2x2 waves, 4x4 frags, 64 B LDS rows —
// those reads run at LDS peak; R3's 80 B pad was a regression, reverted).
// New: per-K-chunk flag check (block-uniform -> barriers legal). Skipping a
// zero chunk is BIT-EXACT: every skipped term is acc += a*0, and x+0.0==x.
__global__ __launch_bounds__(256) void gemm_bt_bf16(
        const unsigned short* __restrict__ A,   // [M][K] bf16 bits
        const unsigned short* __restrict__ B,   // [N][K] bf16 bits (valid where flagged)
        const unsigned int* __restrict__ flags,
        float* __restrict__ C, int M) {
    __shared__ unsigned short sA[128 * 32];     // row-major [m][k], 64 B rows
    __shared__ unsigned short sB[128 * 32];

    const int tid  = threadIdx.x;
    const int w    = tid >> 6;
    const int lane = tid & 63;
    const int quad = lane >> 4;
    const int l16  = lane & 15;
    const int wm   = w >> 1;                    // 2x2 wave grid
    const int wn   = w & 1;

    const int ntile = blockIdx.x & 63;          // N/128 = 64
    const int mtile = blockIdx.x >> 6;
    const int m0 = mtile * 128;
    const int n0 = ntile * 128;

    const unsigned int f0 = flags[ntile * 4 + 0];
    const unsigned int f1 = flags[ntile * 4 + 1];
    const unsigned int f2 = flags[ntile * 4 + 2];
    const unsigned int f3 = flags[ntile * 4 + 3];

    f32x4 acc[4][4];
    const f32x4 z = {0.f, 0.f, 0.f, 0.f};
#pragma unroll
    for (int i = 0; i < 4; ++i)
#pragma unroll
        for (int j = 0; j < 4; ++j) acc[i][j] = z;

    const char* Abase = (const char*)A;
    const char* Bbase = (const char*)B;
    char* sAb = (char*)sA;
    char* sBb = (char*)sB;

    for (int k0 = 0; k0 < K_DIM; k0 += 32) {
        int ch = k0 >> 5;
        unsigned int word = (ch < 64) ? ((ch < 32) ? f0 : f1)
                                      : ((ch < 96) ? f2 : f3);
        if (!((word >> (ch & 31)) & 1u)) continue;   // block-uniform skip

#pragma unroll
        for (int p = 0; p < 2; ++p) {
            int c   = p * 256 + tid;
            int row = c >> 2;
            int kc  = c & 3;
            const char* ga = Abase + ((size_t)(m0 + row) * K_DIM + k0) * 2 + kc * 16;
            const char* gb = Bbase + ((size_t)(n0 + row) * K_DIM + k0) * 2 + kc * 16;
            char* la = sAb + p * 4096 + w * 1024;
            char* lb = sBb + p * 4096 + w * 1024;
            __builtin_amdgcn_global_load_lds((const __attribute__((address_space(1))) void*)ga,
                                             (__attribute__((address_space(3))) void*)la, 16, 0, 0);
            __builtin_amdgcn_global_load_lds((const __attribute__((address_space(1))) void*)gb,
                                             (__attribute__((address_space(3))) void*)lb, 16, 0, 0);
        }
        __syncthreads();

        bf16x8 af[4], bf[4];
#pragma unroll
        for (int i = 0; i < 4; ++i) {
            af[i] = *(const bf16x8*)(sAb + ((size_t)(wm * 64 + i * 16 + l16) * 32 + quad * 8) * 2);
            bf[i] = *(const bf16x8*)(sBb + ((size_t)(wn * 64 + i * 16 + l16) * 32 + quad * 8) * 2);
        }
#pragma unroll
        for (int mi = 0; mi < 4; ++mi)
#pragma unroll
            for (int ni = 0; ni < 4; ++ni)
                acc[mi][ni] = __builtin_amdgcn_mfma_f32_16x16x32_bf16(af[mi], bf[ni], acc[mi][ni], 0, 0, 0);
        __syncthreads();
    }

    // epilogue: D row = m (quad*4+reg), col = n (lane&15)  [verified mapping, m89/m91]
#pragma unroll
    for (int mi = 0; mi < 4; ++mi) {
#pragma unroll
        for (int ni = 0; ni < 4; ++ni) {
            int row = m0 + wm * 64 + mi * 16 + quad * 4;
            int col = n0 + wn * 64 + ni * 16 + l16;
#pragma unroll
            for (int r = 0; r < 4; ++r)
                C[(size_t)(row + r) * N_DIM + col] = acc[mi][ni][r];
        }
    }
}

// ---------- fallback (ws too small): quantize W in place (fp32), fp32 tiled GEMM ----------
__global__ void quant_w_inplace(float* W, const float* __restrict__ scale_p, int n4) {
    const float s = scale_p[0];
    int idx    = blockIdx.x * blockDim.x + threadIdx.x;
    int stride = gridDim.x * blockDim.x;
    float4* W4 = (float4*)W;
    for (int i = idx; i < n4; i += stride) {
        float4 w = W4[i];
        w.x = quantize1(w.x, s); w.y = quantize1(w.y, s);
        w.z = quantize1(w.z, s); w.w = quantize1(w.w, s);
        W4[i] = w;
    }
}

__global__ __launch_bounds__(256) void gemm_fp32_fb(const float* __restrict__ A,
                                                    const float* __restrict__ B,
                                                    float* __restrict__ C, int M) {
    __shared__ float sA[64][17];
    __shared__ float sB[64][17];
    int tid = threadIdx.x;
    int tx = tid & 15, ty = tid >> 4;
    int n0 = (blockIdx.x & 127) * 64;          // N/64 = 128
    int m0 = (blockIdx.x >> 7) * 64;
    float acc[4][4] = {};
    for (int k0 = 0; k0 < K_DIM; k0 += 16) {
#pragma unroll
        for (int i = 0; i < 4; ++i) {
            int e = tid + i * 256;
            int r = e >> 4, c = e & 15;
            sA[r][c] = A[(size_t)(m0 + r) * K_DIM + k0 + c];
            sB[r][c] = B[(size_t)(n0 + r) * K_DIM + k0 + c];
        }
        __syncthreads();
#pragma unroll
        for (int kk = 0; kk < 16; ++kk) {
            float a[4], b[4];
#pragma unroll
            for (int i = 0; i < 4; ++i) { a[i] = sA[ty * 4 + i][kk]; b[i] = sB[tx * 4 + i][kk]; }
#pragma unroll
            for (int i = 0; i < 4; ++i)
#pragma unroll
                for (int j = 0; j < 4; ++j) acc[i][j] += a[i] * b[j];
        }
        __syncthreads();
    }
#pragma unroll
    for (int i = 0; i < 4; ++i)
#pragma unroll
        for (int j = 0; j < 4; ++j)
            C[(size_t)(m0 + ty * 4 + i) * N_DIM + n0 + tx * 4 + j] = acc[i][j];
}

extern "C" void kernel_launch(void* const* d_in, const int* in_sizes, int n_in,
                              void* d_out, int out_size, void* d_ws, size_t ws_size,
                              hipStream_t stream) {
    const float* x     = (const float*)d_in[0];
    const float* W     = (const float*)d_in[1];
    const float* scale = (const float*)d_in[2];
    float* out = (float*)d_out;

    const int M = in_sizes[0] / K_DIM;                       // 1024
    const size_t wq_bytes = (size_t)N_DIM * K_DIM * 2;       // 64 MiB
    const size_t xb_bytes = (size_t)M * K_DIM * 2;           // 8 MiB
    const size_t fl_bytes = (size_t)NTILES * 4 * sizeof(unsigned int);  // 1 KiB

    if (ws_size >= wq_bytes + xb_bytes + fl_bytes && (M % 128) == 0) {
        unsigned short* Wq = (unsigned short*)d_ws;
        unsigned short* Xb = (unsigned short*)((char*)d_ws + wq_bytes);
        unsigned int* flags = (unsigned int*)((char*)d_ws + wq_bytes + xb_bytes);
        int nW4 = (N_DIM * K_DIM) / 4;
        int nX4 = (M * K_DIM) / 4;
        hipMemsetAsync(flags, 0, fl_bytes, stream);
        hipLaunchKernelGGL(quant_w_kernel, dim3(2048), dim3(256), 0, stream, W, scale, Wq, flags, nW4);
        hipLaunchKernelGGL(conv_x_kernel, dim3(1024), dim3(256), 0, stream, x, Xb, nX4);
        hipLaunchKernelGGL(gemm_bt_bf16, dim3((M / 128) * (N_DIM / 128)), dim3(256), 0, stream,
                           Xb, Wq, flags, out, M);
    } else {
        int nW4 = (N_DIM * K_DIM) / 4;
        hipLaunchKernelGGL(quant_w_inplace, dim3(2048), dim3(256), 0, stream,
                           (float*)W, scale, nW4);
        hipLaunchKernelGGL(gemm_fp32_fb, dim3((M / 64) * (N_DIM / 64)), dim3(256), 0, stream,
                           x, W, out, M);
    }
}

// Round 5
// 219.225 us; speedup vs baseline: 1.4693x; 1.0129x over previous
//
#include <hip/hip_runtime.h>
#include <hip/hip_bf16.h>
#include <stdint.h>

#define K_DIM 4096
#define N_DIM 8192
#define NTILES (N_DIM / 128)          // 64 B-row tiles
#define KCHUNKS (K_DIM / 32)          // 128 K chunks (BK=32)
// flags: bit (ntile, kchunk) set iff that 128x32 tile of quantized B has any nonzero.
// Layout: flags[ntile*4 + kchunk/32] bit (kchunk%32). 64*4 uints = 1 KB.

typedef __attribute__((ext_vector_type(8))) __bf16 bf16x8;
typedef __attribute__((ext_vector_type(4))) float f32x4;

// ---------- quantization: nearest of {0,±1,±.5,±.333333,±.2,±.142857,±.090909,±.076923} ----------
// Tie-break matches the reference's first-min LUT scan:
//   boundary to 0 (index 0 first) -> strict >; between nonzero magnitudes -> >=
// Takes the pre-scaled value ws = w * (1/scale); quantized result is v*scale.
__device__ __forceinline__ float quantize_ws(float ws, float scale) {
    float a  = fabsf(ws);
    float v  = 0.0f;
    v = (a >  0.0384615f) ? 0.076923f : v;
    v = (a >= 0.0839160f) ? 0.090909f : v;
    v = (a >= 0.1168830f) ? 0.142857f : v;
    v = (a >= 0.1714285f) ? 0.2f      : v;
    v = (a >= 0.2666665f) ? 0.333333f : v;
    v = (a >= 0.4166665f) ? 0.5f      : v;
    v = (a >= 0.75f)      ? 1.0f      : v;
    v = copysignf(v, ws);
    return v * scale;
}

__device__ __forceinline__ unsigned short to_bf16(float f) {
    unsigned int u = __float_as_uint(f);
    u += 0x7FFFu + ((u >> 16) & 1u);   // RNE
    return (unsigned short)(u >> 16);
}

// ---------- pass 1a: quantize W (fp32) -> bf16 Wq + sparsity flags ----------
// Fast path (the common case for this weight distribution): whole wave's 256
// elements quantize to 0 -> ~12 VALU/iter, HBM-bound. Slow path (any lane has
// |w*inv| above the first threshold): full LUT chain, write Wq quads with a
// nonzero, wave-OR the chunk mask, one atomicOr per wave. A wave spans 256
// consecutive cols inside one row and one 32-chunk flag word (base%64==0).
// inv = 1/scale is hoisted; ws = w*inv feeds BOTH the check and the slow path,
// so the flag/value decisions are self-consistent (and bit-exact at scale=1).
__global__ void quant_w_kernel(const float* __restrict__ W,
                               const float* __restrict__ scale_p,
                               unsigned short* __restrict__ Wq,
                               unsigned int* __restrict__ flags, int n4) {
    const float s   = scale_p[0];
    const float inv = 1.0f / s;
    int idx    = blockIdx.x * blockDim.x + threadIdx.x;
    int stride = gridDim.x * blockDim.x;
    const float4* W4 = (const float4*)W;
    ushort4* Q4 = (ushort4*)Wq;
    for (int i = idx; i < n4; i += stride) {
        float4 w = W4[i];
        float wx = w.x * inv, wy = w.y * inv, wz = w.z * inv, ww = w.w * inv;
        float amax = fmaxf(fmaxf(fabsf(wx), fabsf(wy)), fmaxf(fabsf(wz), fabsf(ww)));
        bool big = amax > 0.0384615f;          // == "this quad has a nonzero quant"
        if (__ballot(big)) {                   // rare slow path
            if (big) {
                ushort4 q;
                q.x = to_bf16(quantize_ws(wx, s));
                q.y = to_bf16(quantize_ws(wy, s));
                q.z = to_bf16(quantize_ws(wz, s));
                q.w = to_bf16(quantize_ws(ww, s));
                Q4[i] = q;
            }
            int col    = (i << 2) & (K_DIM - 1);
            int row    = (i << 2) >> 12;       // /K_DIM
            int kchunk = col >> 5;
            int ntile  = row >> 7;
            unsigned int mask = big ? (1u << (kchunk & 31)) : 0u;
#pragma unroll
            for (int off = 32; off; off >>= 1) mask |= __shfl_down(mask, off, 64);
            if (((threadIdx.x & 63) == 0) && mask)
                atomicOr(&flags[ntile * 4 + (kchunk >> 5)], mask);
        }
    }
}

// ---------- pass 1b: convert x (fp32) -> bf16 in d_ws ----------
__global__ void conv_x_kernel(const float* __restrict__ X,
                              unsigned short* __restrict__ Xb, int n4) {
    int idx    = blockIdx.x * blockDim.x + threadIdx.x;
    int stride = gridDim.x * blockDim.x;
    const float4* X4 = (const float4*)X;
    ushort4* Q4 = (ushort4*)Xb;
    for (int i = idx; i < n4; i += stride) {
        float4 w = X4[i];
        ushort4 q;
        q.x = to_bf16(w.x); q.y = to_bf16(w.y);
        q.z = to_bf16(w.z); q.w = to_bf16(w.w);
        Q4[i] = q;
    }
}

// ---------- pass 2: sparse-aware bf16 GEMM, C = A * Bq^T ----------
// R1 structure (128x128 tile, BK=32, 2x2 waves, 4x4 frags, 64 B LDS rows).
// Per-K-chunk flag check (block-uniform -> barriers legal). Skipping a zero
// chunk is BIT-EXACT: every skipped term is acc += a*0, and x+0.0==x.
__global__ __launch_bounds__(256) void gemm_bt_bf16(
        const unsigned short* __restrict__ A,   // [M][K] bf16 bits
        const unsigned short* __restrict__ B,   // [N][K] bf16 bits (valid where flagged)
        const unsigned int* __restrict__ flags,
        float* __restrict__ C, int M) {
    __shared__ unsigned short sA[128 * 32];     // row-major [m][k], 64 B rows
    __shared__ unsigned short sB[128 * 32];

    const int tid  = threadIdx.x;
    const int w    = tid >> 6;
    const int lane = tid & 63;
    const int quad = lane >> 4;
    const int l16  = lane & 15;
    const int wm   = w >> 1;                    // 2x2 wave grid
    const int wn   = w & 1;

    const int ntile = blockIdx.x & 63;          // N/128 = 64
    const int mtile = blockIdx.x >> 6;
    const int m0 = mtile * 128;
    const int n0 = ntile * 128;

    const unsigned int f0 = flags[ntile * 4 + 0];
    const unsigned int f1 = flags[ntile * 4 + 1];
    const unsigned int f2 = flags[ntile * 4 + 2];
    const unsigned int f3 = flags[ntile * 4 + 3];

    f32x4 acc[4][4];
    const f32x4 z = {0.f, 0.f, 0.f, 0.f};
#pragma unroll
    for (int i = 0; i < 4; ++i)
#pragma unroll
        for (int j = 0; j < 4; ++j) acc[i][j] = z;

    const char* Abase = (const char*)A;
    const char* Bbase = (const char*)B;
    char* sAb = (char*)sA;
    char* sBb = (char*)sB;

    for (int k0 = 0; k0 < K_DIM; k0 += 32) {
        int ch = k0 >> 5;
        unsigned int word = (ch < 64) ? ((ch < 32) ? f0 : f1)
                                      : ((ch < 96) ? f2 : f3);
        if (!((word >> (ch & 31)) & 1u)) continue;   // block-uniform skip

#pragma unroll
        for (int p = 0; p < 2; ++p) {
            int c   = p * 256 + tid;
            int row = c >> 2;
            int kc  = c & 3;
            const char* ga = Abase + ((size_t)(m0 + row) * K_DIM + k0) * 2 + kc * 16;
            const char* gb = Bbase + ((size_t)(n0 + row) * K_DIM + k0) * 2 + kc * 16;
            char* la = sAb + p * 4096 + w * 1024;
            char* lb = sBb + p * 4096 + w * 1024;
            __builtin_amdgcn_global_load_lds((const __attribute__((address_space(1))) void*)ga,
                                             (__attribute__((address_space(3))) void*)la, 16, 0, 0);
            __builtin_amdgcn_global_load_lds((const __attribute__((address_space(1))) void*)gb,
                                             (__attribute__((address_space(3))) void*)lb, 16, 0, 0);
        }
        __syncthreads();

        bf16x8 af[4], bf[4];
#pragma unroll
        for (int i = 0; i < 4; ++i) {
            af[i] = *(const bf16x8*)(sAb + ((size_t)(wm * 64 + i * 16 + l16) * 32 + quad * 8) * 2);
            bf[i] = *(const bf16x8*)(sBb + ((size_t)(wn * 64 + i * 16 + l16) * 32 + quad * 8) * 2);
        }
#pragma unroll
        for (int mi = 0; mi < 4; ++mi)
#pragma unroll
            for (int ni = 0; ni < 4; ++ni)
                acc[mi][ni] = __builtin_amdgcn_mfma_f32_16x16x32_bf16(af[mi], bf[ni], acc[mi][ni], 0, 0, 0);
        __syncthreads();
    }

    // epilogue: D row = m (quad*4+reg), col = n (lane&15)  [verified mapping, m89/m91]
#pragma unroll
    for (int mi = 0; mi < 4; ++mi) {
#pragma unroll
        for (int ni = 0; ni < 4; ++ni) {
            int row = m0 + wm * 64 + mi * 16 + quad * 4;
            int col = n0 + wn * 64 + ni * 16 + l16;
#pragma unroll
            for (int r = 0; r < 4; ++r)
                C[(size_t)(row + r) * N_DIM + col] = acc[mi][ni][r];
        }
    }
}

// ---------- fallback (ws too small): quantize W in place (fp32), fp32 tiled GEMM ----------
__global__ void quant_w_inplace(float* W, const float* __restrict__ scale_p, int n4) {
    const float s   = scale_p[0];
    const float inv = 1.0f / s;
    int idx    = blockIdx.x * blockDim.x + threadIdx.x;
    int stride = gridDim.x * blockDim.x;
    float4* W4 = (float4*)W;
    for (int i = idx; i < n4; i += stride) {
        float4 w = W4[i];
        w.x = quantize_ws(w.x * inv, s); w.y = quantize_ws(w.y * inv, s);
        w.z = quantize_ws(w.z * inv, s); w.w = quantize_ws(w.w * inv, s);
        W4[i] = w;
    }
}

__global__ __launch_bounds__(256) void gemm_fp32_fb(const float* __restrict__ A,
                                                    const float* __restrict__ B,
                                                    float* __restrict__ C, int M) {
    __shared__ float sA[64][17];
    __shared__ float sB[64][17];
    int tid = threadIdx.x;
    int tx = tid & 15, ty = tid >> 4;
    int n0 = (blockIdx.x & 127) * 64;          // N/64 = 128
    int m0 = (blockIdx.x >> 7) * 64;
    float acc[4][4] = {};
    for (int k0 = 0; k0 < K_DIM; k0 += 16) {
#pragma unroll
        for (int i = 0; i < 4; ++i) {
            int e = tid + i * 256;
            int r = e >> 4, c = e & 15;
            sA[r][c] = A[(size_t)(m0 + r) * K_DIM + k0 + c];
            sB[r][c] = B[(size_t)(n0 + r) * K_DIM + k0 + c];
        }
        __syncthreads();
#pragma unroll
        for (int kk = 0; kk < 16; ++kk) {
            float a[4], b[4];
#pragma unroll
            for (int i = 0; i < 4; ++i) { a[i] = sA[ty * 4 + i][kk]; b[i] = sB[tx * 4 + i][kk]; }
#pragma unroll
            for (int i = 0; i < 4; ++i)
#pragma unroll
                for (int j = 0; j < 4; ++j) acc[i][j] += a[i] * b[j];
        }
        __syncthreads();
    }
#pragma unroll
    for (int i = 0; i < 4; ++i)
#pragma unroll
        for (int j = 0; j < 4; ++j)
            C[(size_t)(m0 + ty * 4 + i) * N_DIM + n0 + tx * 4 + j] = acc[i][j];
}

extern "C" void kernel_launch(void* const* d_in, const int* in_sizes, int n_in,
                              void* d_out, int out_size, void* d_ws, size_t ws_size,
                              hipStream_t stream) {
    const float* x     = (const float*)d_in[0];
    const float* W     = (const float*)d_in[1];
    const float* scale = (const float*)d_in[2];
    float* out = (float*)d_out;

    const int M = in_sizes[0] / K_DIM;                       // 1024
    const size_t wq_bytes = (size_t)N_DIM * K_DIM * 2;       // 64 MiB
    const size_t xb_bytes = (size_t)M * K_DIM * 2;           // 8 MiB
    const size_t fl_bytes = (size_t)NTILES * 4 * sizeof(unsigned int);  // 1 KiB

    if (ws_size >= wq_bytes + xb_bytes + fl_bytes && (M % 128) == 0) {
        unsigned short* Wq = (unsigned short*)d_ws;
        unsigned short* Xb = (unsigned short*)((char*)d_ws + wq_bytes);
        unsigned int* flags = (unsigned int*)((char*)d_ws + wq_bytes + xb_bytes);
        int nW4 = (N_DIM * K_DIM) / 4;
        int nX4 = (M * K_DIM) / 4;
        hipMemsetAsync(flags, 0, fl_bytes, stream);
        hipLaunchKernelGGL(quant_w_kernel, dim3(2048), dim3(256), 0, stream, W, scale, Wq, flags, nW4);
        hipLaunchKernelGGL(conv_x_kernel, dim3(1024), dim3(256), 0, stream, x, Xb, nX4);
        hipLaunchKernelGGL(gemm_bt_bf16, dim3((M / 128) * (N_DIM / 128)), dim3(256), 0, stream,
                           Xb, Wq, flags, out, M);
    } else {
        int nW4 = (N_DIM * K_DIM) / 4;
        hipLaunchKernelGGL(quant_w_inplace, dim3(2048), dim3(256), 0, stream,
                           (float*)W, scale, nW4);
        hipLaunchKernelGGL(gemm_fp32_fb, dim3((M / 64) * (N_DIM / 64)), dim3(256), 0, stream,
                           x, W, out, M);
    }
}

// Round 6
// 215.264 us; speedup vs baseline: 1.4964x; 1.0184x over previous
//
#include <hip/hip_runtime.h>
#include <hip/hip_bf16.h>
#include <stdint.h>

#define K_DIM 4096
#define N_DIM 8192
#define NTILES (N_DIM / 128)          // 64 B-row tiles
#define KCHUNKS (K_DIM / 32)          // 128 K chunks (BK=32)
// flags[0..255]: bit (ntile, kchunk) set iff that 128x32 tile of quantized B has
// any nonzero. Layout: flags[ntile*4 + kchunk/32] bit (kchunk%32).
// flags[256]: anynz — nonzero iff any bit anywhere is set (conv_x early-exit).

typedef __attribute__((ext_vector_type(8))) __bf16 bf16x8;
typedef __attribute__((ext_vector_type(4))) float f32x4;

// ---------- quantization: nearest of {0,±1,±.5,±.333333,±.2,±.142857,±.090909,±.076923} ----------
// Tie-break matches the reference's first-min LUT scan:
//   boundary to 0 (index 0 first) -> strict >; between nonzero magnitudes -> >=
// Takes the pre-scaled value ws = w * (1/scale); quantized result is v*scale.
__device__ __forceinline__ float quantize_ws(float ws, float scale) {
    float a  = fabsf(ws);
    float v  = 0.0f;
    v = (a >  0.0384615f) ? 0.076923f : v;
    v = (a >= 0.0839160f) ? 0.090909f : v;
    v = (a >= 0.1168830f) ? 0.142857f : v;
    v = (a >= 0.1714285f) ? 0.2f      : v;
    v = (a >= 0.2666665f) ? 0.333333f : v;
    v = (a >= 0.4166665f) ? 0.5f      : v;
    v = (a >= 0.75f)      ? 1.0f      : v;
    v = copysignf(v, ws);
    return v * scale;
}

__device__ __forceinline__ unsigned short to_bf16(float f) {
    unsigned int u = __float_as_uint(f);
    u += 0x7FFFu + ((u >> 16) & 1u);   // RNE
    return (unsigned short)(u >> 16);
}

// ---------- pass 1a: quantize W (fp32) -> bf16 Wq + sparsity flags ----------
// Fast path (common for this weight distribution): whole wave's 256 elements
// quantize to 0 -> ~12 VALU/iter, HBM-read-bound. Slow path: full LUT chain,
// write nonzero Wq quads, wave-OR the chunk mask, atomicOr flags + anynz.
// A wave spans 256 consecutive cols inside one row and one 32-chunk flag word.
__global__ void quant_w_kernel(const float* __restrict__ W,
                               const float* __restrict__ scale_p,
                               unsigned short* __restrict__ Wq,
                               unsigned int* __restrict__ flags, int n4) {
    const float s   = scale_p[0];
    const float inv = 1.0f / s;
    int idx    = blockIdx.x * blockDim.x + threadIdx.x;
    int stride = gridDim.x * blockDim.x;
    const float4* W4 = (const float4*)W;
    ushort4* Q4 = (ushort4*)Wq;
    for (int i = idx; i < n4; i += stride) {
        float4 w = W4[i];
        float wx = w.x * inv, wy = w.y * inv, wz = w.z * inv, ww = w.w * inv;
        float amax = fmaxf(fmaxf(fabsf(wx), fabsf(wy)), fmaxf(fabsf(wz), fabsf(ww)));
        bool big = amax > 0.0384615f;          // == "this quad has a nonzero quant"
        if (__ballot(big)) {                   // rare slow path
            if (big) {
                ushort4 q;
                q.x = to_bf16(quantize_ws(wx, s));
                q.y = to_bf16(quantize_ws(wy, s));
                q.z = to_bf16(quantize_ws(wz, s));
                q.w = to_bf16(quantize_ws(ww, s));
                Q4[i] = q;
            }
            int col    = (i << 2) & (K_DIM - 1);
            int row    = (i << 2) >> 12;       // /K_DIM
            int kchunk = col >> 5;
            int ntile  = row >> 7;
            unsigned int mask = big ? (1u << (kchunk & 31)) : 0u;
#pragma unroll
            for (int off = 32; off; off >>= 1) mask |= __shfl_down(mask, off, 64);
            if (((threadIdx.x & 63) == 0) && mask) {
                atomicOr(&flags[ntile * 4 + (kchunk >> 5)], mask);
                atomicOr(&flags[NTILES * 4], 1u);          // anynz
            }
        }
    }
}

// ---------- pass 1b: convert x (fp32) -> bf16 (skipped if W quantizes to 0) ----------
// Runs AFTER quant_w on the same stream (kernel-boundary release/acquire makes
// the flag visible). If no B-tile has a nonzero, gemm never reads Xb -> exit.
__global__ void conv_x_kernel(const float* __restrict__ X,
                              unsigned short* __restrict__ Xb,
                              const unsigned int* __restrict__ flags, int n4) {
    if (flags[NTILES * 4] == 0u) return;       // block-uniform early exit
    int idx    = blockIdx.x * blockDim.x + threadIdx.x;
    int stride = gridDim.x * blockDim.x;
    const float4* X4 = (const float4*)X;
    ushort4* Q4 = (ushort4*)Xb;
    for (int i = idx; i < n4; i += stride) {
        float4 w = X4[i];
        ushort4 q;
        q.x = to_bf16(w.x); q.y = to_bf16(w.y);
        q.z = to_bf16(w.z); q.w = to_bf16(w.w);
        Q4[i] = q;
    }
}

// ---------- pass 2: sparse-aware bf16 GEMM, C = A * Bq^T ----------
// R1 structure (128x128 tile, BK=32, 2x2 waves, 4x4 frags, 64 B LDS rows).
// Per-K-chunk flag check (block-uniform -> barriers legal). Skipping a zero
// chunk is BIT-EXACT: every skipped term is acc += a*0, and x+0.0==x.
__global__ __launch_bounds__(256) void gemm_bt_bf16(
        const unsigned short* __restrict__ A,   // [M][K] bf16 bits
        const unsigned short* __restrict__ B,   // [N][K] bf16 bits (valid where flagged)
        const unsigned int* __restrict__ flags,
        float* __restrict__ C, int M) {
    __shared__ unsigned short sA[128 * 32];     // row-major [m][k], 64 B rows
    __shared__ unsigned short sB[128 * 32];

    const int tid  = threadIdx.x;
    const int w    = tid >> 6;
    const int lane = tid & 63;
    const int quad = lane >> 4;
    const int l16  = lane & 15;
    const int wm   = w >> 1;                    // 2x2 wave grid
    const int wn   = w & 1;

    const int ntile = blockIdx.x & 63;          // N/128 = 64
    const int mtile = blockIdx.x >> 6;
    const int m0 = mtile * 128;
    const int n0 = ntile * 128;

    const unsigned int f0 = flags[ntile * 4 + 0];
    const unsigned int f1 = flags[ntile * 4 + 1];
    const unsigned int f2 = flags[ntile * 4 + 2];
    const unsigned int f3 = flags[ntile * 4 + 3];

    f32x4 acc[4][4];
    const f32x4 z = {0.f, 0.f, 0.f, 0.f};
#pragma unroll
    for (int i = 0; i < 4; ++i)
#pragma unroll
        for (int j = 0; j < 4; ++j) acc[i][j] = z;

    const char* Abase = (const char*)A;
    const char* Bbase = (const char*)B;
    char* sAb = (char*)sA;
    char* sBb = (char*)sB;

    for (int k0 = 0; k0 < K_DIM; k0 += 32) {
        int ch = k0 >> 5;
        unsigned int word = (ch < 64) ? ((ch < 32) ? f0 : f1)
                                      : ((ch < 96) ? f2 : f3);
        if (!((word >> (ch & 31)) & 1u)) continue;   // block-uniform skip

#pragma unroll
        for (int p = 0; p < 2; ++p) {
            int c   = p * 256 + tid;
            int row = c >> 2;
            int kc  = c & 3;
            const char* ga = Abase + ((size_t)(m0 + row) * K_DIM + k0) * 2 + kc * 16;
            const char* gb = Bbase + ((size_t)(n0 + row) * K_DIM + k0) * 2 + kc * 16;
            char* la = sAb + p * 4096 + w * 1024;
            char* lb = sBb + p * 4096 + w * 1024;
            __builtin_amdgcn_global_load_lds((const __attribute__((address_space(1))) void*)ga,
                                             (__attribute__((address_space(3))) void*)la, 16, 0, 0);
            __builtin_amdgcn_global_load_lds((const __attribute__((address_space(1))) void*)gb,
                                             (__attribute__((address_space(3))) void*)lb, 16, 0, 0);
        }
        __syncthreads();

        bf16x8 af[4], bf[4];
#pragma unroll
        for (int i = 0; i < 4; ++i) {
            af[i] = *(const bf16x8*)(sAb + ((size_t)(wm * 64 + i * 16 + l16) * 32 + quad * 8) * 2);
            bf[i] = *(const bf16x8*)(sBb + ((size_t)(wn * 64 + i * 16 + l16) * 32 + quad * 8) * 2);
        }
#pragma unroll
        for (int mi = 0; mi < 4; ++mi)
#pragma unroll
            for (int ni = 0; ni < 4; ++ni)
                acc[mi][ni] = __builtin_amdgcn_mfma_f32_16x16x32_bf16(af[mi], bf[ni], acc[mi][ni], 0, 0, 0);
        __syncthreads();
    }

    // epilogue: D row = m (quad*4+reg), col = n (lane&15)  [verified mapping, m89/m91]
#pragma unroll
    for (int mi = 0; mi < 4; ++mi) {
#pragma unroll
        for (int ni = 0; ni < 4; ++ni) {
            int row = m0 + wm * 64 + mi * 16 + quad * 4;
            int col = n0 + wn * 64 + ni * 16 + l16;
#pragma unroll
            for (int r = 0; r < 4; ++r)
                C[(size_t)(row + r) * N_DIM + col] = acc[mi][ni][r];
        }
    }
}

// ---------- fallback (ws too small): quantize W in place (fp32), fp32 tiled GEMM ----------
__global__ void quant_w_inplace(float* W, const float* __restrict__ scale_p, int n4) {
    const float s   = scale_p[0];
    const float inv = 1.0f / s;
    int idx    = blockIdx.x * blockDim.x + threadIdx.x;
    int stride = gridDim.x * blockDim.x;
    float4* W4 = (float4*)W;
    for (int i = idx; i < n4; i += stride) {
        float4 w = W4[i];
        w.x = quantize_ws(w.x * inv, s); w.y = quantize_ws(w.y * inv, s);
        w.z = quantize_ws(w.z * inv, s); w.w = quantize_ws(w.w * inv, s);
        W4[i] = w;
    }
}

__global__ __launch_bounds__(256) void gemm_fp32_fb(const float* __restrict__ A,
                                                    const float* __restrict__ B,
                                                    float* __restrict__ C, int M) {
    __shared__ float sA[64][17];
    __shared__ float sB[64][17];
    int tid = threadIdx.x;
    int tx = tid & 15, ty = tid >> 4;
    int n0 = (blockIdx.x & 127) * 64;          // N/64 = 128
    int m0 = (blockIdx.x >> 7) * 64;
    float acc[4][4] = {};
    for (int k0 = 0; k0 < K_DIM; k0 += 16) {
#pragma unroll
        for (int i = 0; i < 4; ++i) {
            int e = tid + i * 256;
            int r = e >> 4, c = e & 15;
            sA[r][c] = A[(size_t)(m0 + r) * K_DIM + k0 + c];
            sB[r][c] = B[(size_t)(n0 + r) * K_DIM + k0 + c];
        }
        __syncthreads();
#pragma unroll
        for (int kk = 0; kk < 16; ++kk) {
            float a[4], b[4];
#pragma unroll
            for (int i = 0; i < 4; ++i) { a[i] = sA[ty * 4 + i][kk]; b[i] = sB[tx * 4 + i][kk]; }
#pragma unroll
            for (int i = 0; i < 4; ++i)
#pragma unroll
                for (int j = 0; j < 4; ++j) acc[i][j] += a[i] * b[j];
        }
        __syncthreads();
    }
#pragma unroll
    for (int i = 0; i < 4; ++i)
#pragma unroll
        for (int j = 0; j < 4; ++j)
            C[(size_t)(m0 + ty * 4 + i) * N_DIM + n0 + tx * 4 + j] = acc[i][j];
}

extern "C" void kernel_launch(void* const* d_in, const int* in_sizes, int n_in,
                              void* d_out, int out_size, void* d_ws, size_t ws_size,
                              hipStream_t stream) {
    const float* x     = (const float*)d_in[0];
    const float* W     = (const float*)d_in[1];
    const float* scale = (const float*)d_in[2];
    float* out = (float*)d_out;

    const int M = in_sizes[0] / K_DIM;                       // 1024
    const size_t wq_bytes = (size_t)N_DIM * K_DIM * 2;       // 64 MiB
    const size_t xb_bytes = (size_t)M * K_DIM * 2;           // 8 MiB
    const size_t fl_bytes = (size_t)(NTILES * 4 + 1) * sizeof(unsigned int);  // 1028 B

    if (ws_size >= wq_bytes + xb_bytes + fl_bytes && (M % 128) == 0) {
        unsigned short* Wq = (unsigned short*)d_ws;
        unsigned short* Xb = (unsigned short*)((char*)d_ws + wq_bytes);
        unsigned int* flags = (unsigned int*)((char*)d_ws + wq_bytes + xb_bytes);
        int nW4 = (N_DIM * K_DIM) / 4;
        int nX4 = (M * K_DIM) / 4;
        hipMemsetAsync(flags, 0, fl_bytes, stream);
        hipLaunchKernelGGL(quant_w_kernel, dim3(2048), dim3(256), 0, stream, W, scale, Wq, flags, nW4);
        hipLaunchKernelGGL(conv_x_kernel, dim3(1024), dim3(256), 0, stream, x, Xb, flags, nX4);
        hipLaunchKernelGGL(gemm_bt_bf16, dim3((M / 128) * (N_DIM / 128)), dim3(256), 0, stream,
                           Xb, Wq, flags, out, M);
    } else {
        int nW4 = (N_DIM * K_DIM) / 4;
        hipLaunchKernelGGL(quant_w_inplace, dim3(2048), dim3(256), 0, stream,
                           (float*)W, scale, nW4);
        hipLaunchKernelGGL(gemm_fp32_fb, dim3((M / 64) * (N_DIM / 64)), dim3(256), 0, stream,
                           x, W, out, M);
    }
}